// Round 6
// baseline (5070.226 us; speedup 1.0000x reference)
//
#include <hip/hip_runtime.h>
#include <stdint.h>
#include <stddef.h>

typedef __attribute__((ext_vector_type(8))) short short8;
typedef __attribute__((ext_vector_type(4))) short short4_t;
typedef __attribute__((ext_vector_type(8))) unsigned short ushort8_t;
typedef __attribute__((ext_vector_type(4))) unsigned short ushort4_t;
typedef __attribute__((ext_vector_type(4))) float f32x4;
typedef __attribute__((ext_vector_type(4))) unsigned uint4_t;

// workspace layout (bytes)
#define XG_BYTES  (134217728ull)          // xg: [1024 t][4 g][1024 n][16 b] bf16
#define HS_BYTES  (33587200ull)           // hs: [1025 t][16 b][1024 k] bf16
#define FLAGS_OFF (XG_BYTES + HS_BYTES)   // 128 flags (WG*4+wave), packed u32
#define WT_OFF    (FLAGS_OFF + 32768ull)  // Wt: [9][1024 n][1024 k] bf16

#define SENT 0x7FC07FC0u                  // bf16 NaN pair — h is finite, never equals this

__device__ __forceinline__ unsigned short f2b(float f){
  unsigned u = __builtin_bit_cast(unsigned, f);
  u += 0x7fffu + ((u >> 16) & 1u);
  return (unsigned short)(u >> 16);
}
__device__ __forceinline__ float b2f(unsigned short b){
  unsigned u = ((unsigned)b) << 16;
  return __builtin_bit_cast(float, u);
}
__device__ __forceinline__ float sigm(float x){ return 1.0f / (1.0f + __expf(-x)); }
__device__ __forceinline__ float tanh_(float x){ return 2.0f / (1.0f + __expf(-2.0f*x)) - 1.0f; }

// ---- coherence-point (MALL) primitives: sc0 sc1 = bypass L1 and L2 --------
__device__ __forceinline__ unsigned ld_u32_mall(const unsigned* p){
  unsigned v;
  asm volatile("global_load_dword %0, %1, off sc0 sc1\n\t"
               "s_waitcnt vmcnt(0)"
               : "=v"(v) : "v"(p) : "memory");
  return v;
}
__device__ __forceinline__ void ld_h8_mall(const unsigned short* p, short8* a){
  asm volatile(
    "global_load_dwordx4 %0, %8, off sc0 sc1\n\t"
    "global_load_dwordx4 %1, %8, off offset:64 sc0 sc1\n\t"
    "global_load_dwordx4 %2, %8, off offset:128 sc0 sc1\n\t"
    "global_load_dwordx4 %3, %8, off offset:192 sc0 sc1\n\t"
    "global_load_dwordx4 %4, %8, off offset:256 sc0 sc1\n\t"
    "global_load_dwordx4 %5, %8, off offset:320 sc0 sc1\n\t"
    "global_load_dwordx4 %6, %8, off offset:384 sc0 sc1\n\t"
    "global_load_dwordx4 %7, %8, off offset:448 sc0 sc1\n\t"
    "s_waitcnt vmcnt(0)"
    : "=&v"(a[0]), "=&v"(a[1]), "=&v"(a[2]), "=&v"(a[3]),
      "=&v"(a[4]), "=&v"(a[5]), "=&v"(a[6]), "=&v"(a[7])
    : "v"(p) : "memory");
}
__device__ __forceinline__ void st_u32_mall(unsigned* p, unsigned v){
  asm volatile("global_store_dword %0, %1, off sc0 sc1"
               :: "v"(p), "v"(v) : "memory");
}

// ---------------- weight transpose+convert: W[k][n] f32 -> Wt[n][k] bf16 ----
__global__ __launch_bounds__(256) void k_prep(
    const float* __restrict__ w0, const float* __restrict__ w1,
    const float* __restrict__ w2, const float* __restrict__ w3,
    const float* __restrict__ w4, const float* __restrict__ w5,
    const float* __restrict__ w6, const float* __restrict__ w7,
    const float* __restrict__ w8, unsigned short* __restrict__ wt)
{
  const int z = blockIdx.z;
  const float* W = (z==0)?w0:(z==1)?w1:(z==2)?w2:(z==3)?w3:(z==4)?w4:
                   (z==5)?w5:(z==6)?w6:(z==7)?w7:w8;
  unsigned short* out = wt + (size_t)z*1024*1024;
  __shared__ float tile[64][65];
  const int k0 = blockIdx.x*64, n0 = blockIdx.y*64;
  const int tid = threadIdx.x;
  {
    const int kk = tid >> 2, nn0 = (tid & 3) * 16;
    const float* src = W + (size_t)(k0+kk)*1024 + n0 + nn0;
    #pragma unroll
    for (int j=0;j<16;j+=4){
      f32x4 v = *(const f32x4*)(src + j);
      tile[kk][nn0+j+0]=v[0]; tile[kk][nn0+j+1]=v[1];
      tile[kk][nn0+j+2]=v[2]; tile[kk][nn0+j+3]=v[3];
    }
  }
  __syncthreads();
  {
    const int nn = tid >> 2, kk0 = (tid & 3) * 16;
    ushort8_t a, b;
    #pragma unroll
    for (int j=0;j<8;++j){ a[j]=f2b(tile[kk0+j][nn]); b[j]=f2b(tile[kk0+8+j][nn]); }
    unsigned short* dst = out + (size_t)(n0+nn)*1024 + k0 + kk0;
    *(ushort8_t*)dst = a;
    *(ushort8_t*)(dst+8) = b;
  }
}

// ---------------- h0 -> hs[0] bf16 ------------------------------------------
__global__ void k_init(const float* __restrict__ h0, unsigned short* __restrict__ hs){
  const int i = blockIdx.x*256 + threadIdx.x;
  hs[i] = f2b(h0[i]);
}

// ---------------- sentinel-fill hs[1..1024] ---------------------------------
__global__ void k_fill(unsigned* __restrict__ hsw){
  const size_t i = (size_t)blockIdx.x*256 + threadIdx.x;   // 2,097,152 threads
  uint4_t v = (uint4_t){SENT, SENT, SENT, SENT};
  *(uint4_t*)(hsw + 8192 + i*4) = v;                       // slot1 starts at word 8192
}

// ---------------- x projections: xg[t][g][n][b] = x @ Wx + bx (bf16 out) ----
__global__ __launch_bounds__(256,2) void k_xproj(
    const float* __restrict__ xF, const float* __restrict__ xI,
    const float* __restrict__ xZ, const float* __restrict__ xO,
    const float* __restrict__ bF, const float* __restrict__ bI,
    const float* __restrict__ bZ, const float* __restrict__ bO,
    const unsigned short* __restrict__ Wt,   // [4][n][k] bf16
    unsigned short* __restrict__ xg)
{
  const int g  = blockIdx.z;
  const int tm = blockIdx.x, tn = blockIdx.y;
  const float* X  = (g==0)?xF:(g==1)?xI:(g==2)?xZ:xO;
  const float* Bp = (g==0)?bF:(g==1)?bI:(g==2)?bZ:bO;
  const unsigned short* Wg = Wt + (size_t)g*1024*1024;

  __shared__ unsigned short Asm[128*32];
  __shared__ unsigned short Bsm[128*32];

  const int tid  = threadIdx.x;
  const int lane = tid & 63, wv = tid >> 6;
  const int l15  = lane & 15, lg = lane >> 4;
  const int wy   = wv >> 1,  wx = wv & 1;

  const int rr = tid >> 1, kq = tid & 1;
  const int ar = tm*128 + rr;
  const int ab = ar & 15, as_ = ar >> 4;
  const float* aptr = X + ((size_t)ab*1024 + as_)*1024 + kq*16;
  const unsigned short* bp_ = Wg + (size_t)(tn*128 + rr)*1024 + kq*16;
  const int s0 = kq*2;
  unsigned short* aw0 = &Asm[rr*32 + (((s0  ) ^ (rr&3))<<3)];
  unsigned short* aw1 = &Asm[rr*32 + (((s0+1) ^ (rr&3))<<3)];
  unsigned short* bw0 = &Bsm[rr*32 + (((s0  ) ^ (rr&3))<<3)];
  unsigned short* bw1 = &Bsm[rr*32 + (((s0+1) ^ (rr&3))<<3)];

  f32x4 acc[4][4];
  #pragma unroll
  for (int m=0;m<4;++m)
    #pragma unroll
    for (int q=0;q<4;++q) acc[m][q] = (f32x4){0.f,0.f,0.f,0.f};

  for (int k0=0; k0<1024; k0+=32){
    const float* ap = aptr + k0;
    f32x4 v0 = *(const f32x4*)(ap + 0);
    f32x4 v1 = *(const f32x4*)(ap + 4);
    f32x4 v2 = *(const f32x4*)(ap + 8);
    f32x4 v3 = *(const f32x4*)(ap + 12);
    ushort8_t pa, pb;
    #pragma unroll
    for (int j=0;j<4;++j){ pa[j]=f2b(v0[j]); pa[4+j]=f2b(v1[j]); pb[j]=f2b(v2[j]); pb[4+j]=f2b(v3[j]); }
    *(ushort8_t*)aw0 = pa;
    *(ushort8_t*)aw1 = pb;
    ushort8_t q0 = *(const ushort8_t*)(bp_ + k0);
    ushort8_t q1 = *(const ushort8_t*)(bp_ + k0 + 8);
    *(ushort8_t*)bw0 = q0;
    *(ushort8_t*)bw1 = q1;
    __syncthreads();

    short8 af[4], bf_[4];
    #pragma unroll
    for (int m=0;m<4;++m){
      int row = wy*64 + m*16 + l15;
      af[m] = *(const short8*)&Asm[row*32 + ((lg ^ (row&3))<<3)];
    }
    #pragma unroll
    for (int q=0;q<4;++q){
      int row = wx*64 + q*16 + l15;
      bf_[q] = *(const short8*)&Bsm[row*32 + ((lg ^ (row&3))<<3)];
    }
    #pragma unroll
    for (int m=0;m<4;++m)
      #pragma unroll
      for (int q=0;q<4;++q)
        acc[m][q] = __builtin_amdgcn_mfma_f32_16x16x32_bf16(af[m], bf_[q], acc[m][q], 0,0,0);
    __syncthreads();
  }

  #pragma unroll
  for (int m=0;m<4;++m){
    const int t = tm*8 + wy*4 + m;
    #pragma unroll
    for (int q=0;q<4;++q){
      const int n = tn*128 + wx*64 + q*16 + l15;
      const float bias = Bp[n];
      f32x4 v = acc[m][q];
      ushort4_t pk;
      #pragma unroll
      for (int r=0;r<4;++r) pk[r] = f2b(v[r] + bias);
      *(ushort4_t*)(xg + (size_t)((t*4+g)*1024 + n)*16 + lg*4) = pk;
    }
  }
}

// ---------------- persistent recurrence --------------------------------------
// 32 WGs; WG wg owns output cols [wg*32,+32); wave wv holds K-slice [wv*256,+256)
// (256 weight VGPRs, 64 MFMA/step). Consumer: speculative bulk load (1 MALL RT
// steady state); on sentinel, cheap per-(WG,wave) flag poll then one reload.
// Producer: wave wv gates ONLY batch rows lg*4+wv, stores them + flag, no drain.
// Raw lgkmcnt barrier (no VMEM drain); xq prefetched one step ahead.
__global__ __launch_bounds__(256,1) void k_recur(
    const unsigned short* __restrict__ WtR,   // [4][1024 n][1024 k] bf16 (Fh,Ih,Zh,Oh)
    const float* __restrict__ bfh, const float* __restrict__ bih,
    const float* __restrict__ bzh, const float* __restrict__ boh,
    const float* __restrict__ c0,
    const unsigned short* __restrict__ xg,
    unsigned short* __restrict__ hs,
    unsigned* __restrict__ flags,
    float* __restrict__ oc, float* __restrict__ oh)
{
  const int wg   = blockIdx.x;          // 0..31
  const int tid  = threadIdx.x;
  const int wv   = tid >> 6, lane = tid & 63;
  const int l15  = lane & 15, lg = lane >> 4;
  const int n0   = wg*32;
  const int nA   = n0 + l15;            // e=0 column
  const int nB   = n0 + 16 + l15;       // e=1 column
  const int row  = lg*4 + wv;           // batch row this wave gates/stores
  const int sh   = wv * 16;             // comp-extract shift for xq words

  // register-resident recurrent weights (pre-transposed bf16, coalesced)
  short8 wf[4][2][8];
  #pragma unroll
  for (int g=0; g<4; ++g)
    #pragma unroll
    for (int e=0; e<2; ++e){
      const unsigned short* wp = WtR + (size_t)g*1048576
                               + (size_t)(n0 + e*16 + l15)*1024 + wv*256 + lg*8;
      #pragma unroll
      for (int c=0; c<8; ++c)
        wf[g][e][c] = *(const short8*)(wp + c*32);
    }

  // gating state: only row `row`, cols nA/nB
  float cstA = c0[(size_t)row*1024 + nA];
  float cstB = c0[(size_t)row*1024 + nB];
  float biasA[4] = {bfh[nA], bih[nA], bzh[nA], boh[nA]};
  float biasB[4] = {bfh[nB], bih[nB], bzh[nB], boh[nB]};

  // partials as component planes: [pb][wave][gate][e][comp][lane]  (64 KB)
  __shared__ float part[2][4][4][2][4][64];

  unsigned* hsw = (unsigned*)hs;

  // xq prologue (t = 0)
  short4_t xqA[4], xqB[4];
  #pragma unroll
  for (int g=0; g<4; ++g){
    xqA[g] = *(const short4_t*)(xg + (size_t)(g*1024 + nA)*16 + lg*4);
    xqB[g] = *(const short4_t*)(xg + (size_t)(g*1024 + nB)*16 + lg*4);
  }

  float hvA = 0.f, hvB = 0.f;
  for (int t=0; t<1024; ++t){
    // 1. speculative bulk A-fragment load; flag-poll recovery on sentinel
    const unsigned short* hp = hs + (size_t)t*16384 + (size_t)l15*1024 + wv*256 + lg*8;
    short8 a[8];
    ld_h8_mall(hp, a);
    for(;;){
      bool bad = false;
      #pragma unroll
      for (int c=0;c<8;++c){
        uint4_t q = __builtin_bit_cast(uint4_t, a[c]);
        bad |= (q[0]==SENT)|(q[1]==SENT)|(q[2]==SENT)|(q[3]==SENT);
      }
      if (!__any(bad)) break;
      unsigned fv;
      do { fv = ld_u32_mall(flags + wv*32 + (lane & 31)); }
      while (!__all((int)(fv >= (unsigned)t)));
      ld_h8_mall(hp, a);
    }

    // 2. xq(t+1) prefetch (plain cached loads; in flight across the barrier)
    short4_t xqA_n[4], xqB_n[4];
    if (t < 1023){
      const size_t tb = (size_t)(t+1)*4096;
      #pragma unroll
      for (int g=0; g<4; ++g){
        xqA_n[g] = *(const short4_t*)(xg + (tb + (size_t)g*1024 + nA)*16 + lg*4);
        xqB_n[g] = *(const short4_t*)(xg + (tb + (size_t)g*1024 + nB)*16 + lg*4);
      }
    }

    // 3. MFMA: 4 gates x 2 col-groups x 8 K-chunks
    f32x4 acc[4][2];
    #pragma unroll
    for (int g=0;g<4;++g){ acc[g][0]=(f32x4){0,0,0,0}; acc[g][1]=(f32x4){0,0,0,0}; }
    #pragma unroll
    for (int c=0;c<8;++c)
      #pragma unroll
      for (int g=0;g<4;++g){
        acc[g][0] = __builtin_amdgcn_mfma_f32_16x16x32_bf16(a[c], wf[g][0][c], acc[g][0], 0,0,0);
        acc[g][1] = __builtin_amdgcn_mfma_f32_16x16x32_bf16(a[c], wf[g][1][c], acc[g][1], 0,0,0);
      }

    // 4. partial store (component planes) + raw barrier (no VMEM drain)
    const int pb = t & 1;
    #pragma unroll
    for (int g=0;g<4;++g)
      #pragma unroll
      for (int e=0;e<2;++e)
        #pragma unroll
        for (int cm=0;cm<4;++cm)
          part[pb][wv][g][e][cm][lane] = acc[g][e][cm];
    asm volatile("s_waitcnt lgkmcnt(0)" ::: "memory");
    __builtin_amdgcn_s_barrier();

    // 5. reduce: only component wv (this wave's batch row)
    float rgA[4], rgB[4];
    #pragma unroll
    for (int g=0;g<4;++g){
      rgA[g] = part[pb][0][g][0][wv][lane] + part[pb][1][g][0][wv][lane]
             + part[pb][2][g][0][wv][lane] + part[pb][3][g][0][wv][lane];
      rgB[g] = part[pb][0][g][1][wv][lane] + part[pb][1][g][1][wv][lane]
             + part[pb][2][g][1][wv][lane] + part[pb][3][g][1][wv][lane];
    }

    // 6. gate row `row` for both column groups
    {
      float pf = rgA[0] + b2f((unsigned short)(__builtin_bit_cast(unsigned long long, xqA[0]) >> sh)) + biasA[0];
      float pi = rgA[1] + b2f((unsigned short)(__builtin_bit_cast(unsigned long long, xqA[1]) >> sh)) + biasA[1];
      float pz = rgA[2] + b2f((unsigned short)(__builtin_bit_cast(unsigned long long, xqA[2]) >> sh)) + biasA[2];
      float po = rgA[3] + b2f((unsigned short)(__builtin_bit_cast(unsigned long long, xqA[3]) >> sh)) + biasA[3];
      float fg = sigm(pf), ig = sigm(pi), zg = tanh_(pz), og = sigm(po);
      float cn = fg*cstA + ig*zg;
      cstA = cn;
      hvA = og * tanh_(cn);
    }
    {
      float pf = rgB[0] + b2f((unsigned short)(__builtin_bit_cast(unsigned long long, xqB[0]) >> sh)) + biasB[0];
      float pi = rgB[1] + b2f((unsigned short)(__builtin_bit_cast(unsigned long long, xqB[1]) >> sh)) + biasB[1];
      float pz = rgB[2] + b2f((unsigned short)(__builtin_bit_cast(unsigned long long, xqB[2]) >> sh)) + biasB[2];
      float po = rgB[3] + b2f((unsigned short)(__builtin_bit_cast(unsigned long long, xqB[3]) >> sh)) + biasB[3];
      float fg = sigm(pf), ig = sigm(pi), zg = tanh_(pz), og = sigm(po);
      float cn = fg*cstB + ig*zg;
      cstB = cn;
      hvB = og * tanh_(cn);
    }

    // 7. pack bf16 pairs across lane^1; even l15 lanes store; then flag
    {
      unsigned mA  = (unsigned)f2b(hvA);
      unsigned nbA = (unsigned)__shfl_xor(mA, 1);
      unsigned mB  = (unsigned)f2b(hvB);
      unsigned nbB = (unsigned)__shfl_xor(mB, 1);
      if ((l15 & 1) == 0){
        unsigned* base = hsw + (size_t)(t+1)*8192 + (size_t)row*512;
        st_u32_mall(base + (nA >> 1), mA | (nbA << 16));
        st_u32_mall(base + (nB >> 1), mB | (nbB << 16));
      }
      if (lane == 0)
        st_u32_mall(flags + wg*4 + wv, (unsigned)(t+1));
    }

    // 8. rotate xq pipeline
    #pragma unroll
    for (int g=0; g<4; ++g){ xqA[g] = xqA_n[g]; xqB[g] = xqB_n[g]; }
  }

  // final state: wave wv owns batch row `row`
  oc[(size_t)row*1024 + nA] = cstA;
  oc[(size_t)row*1024 + nB] = cstB;
  oh[(size_t)row*1024 + nA] = hvA;
  oh[(size_t)row*1024 + nB] = hvB;
}

// ---------------- post projection: y[b][s][n] = hs[1..] @ Wpost + bpost -----
__global__ __launch_bounds__(256,2) void k_post(
    const unsigned short* __restrict__ hs,
    const unsigned short* __restrict__ Wt,   // post slice at +4M
    const float* __restrict__ bpost,
    float* __restrict__ y)
{
  const int tm = blockIdx.x, tn = blockIdx.y;
  __shared__ unsigned short Asm[128*32];
  __shared__ unsigned short Bsm[128*32];

  const int tid  = threadIdx.x;
  const int lane = tid & 63, wv = tid >> 6;
  const int l15  = lane & 15, lg = lane >> 4;
  const int wy   = wv >> 1,  wx = wv & 1;

  const int rr = tid >> 1, kq = tid & 1;
  const unsigned short* aptr = hs + 16384 + (size_t)(tm*128 + rr)*1024 + kq*16;
  const unsigned short* bp_  = Wt + (size_t)4*1024*1024 + (size_t)(tn*128 + rr)*1024 + kq*16;
  const int s0 = kq*2;
  unsigned short* aw0 = &Asm[rr*32 + (((s0  ) ^ (rr&3))<<3)];
  unsigned short* aw1 = &Asm[rr*32 + (((s0+1) ^ (rr&3))<<3)];
  unsigned short* bw0 = &Bsm[rr*32 + (((s0  ) ^ (rr&3))<<3)];
  unsigned short* bw1 = &Bsm[rr*32 + (((s0+1) ^ (rr&3))<<3)];

  f32x4 acc[4][4];
  #pragma unroll
  for (int m=0;m<4;++m)
    #pragma unroll
    for (int q=0;q<4;++q) acc[m][q] = (f32x4){0.f,0.f,0.f,0.f};

  for (int k0=0; k0<1024; k0+=32){
    ushort8_t a0 = *(const ushort8_t*)(aptr + k0);
    ushort8_t a1 = *(const ushort8_t*)(aptr + k0 + 8);
    *(ushort8_t*)aw0 = a0;
    *(ushort8_t*)aw1 = a1;
    ushort8_t q0 = *(const ushort8_t*)(bp_ + k0);
    ushort8_t q1 = *(const ushort8_t*)(bp_ + k0 + 8);
    *(ushort8_t*)bw0 = q0;
    *(ushort8_t*)bw1 = q1;
    __syncthreads();

    short8 af[4], bf_[4];
    #pragma unroll
    for (int m=0;m<4;++m){
      int row = wy*64 + m*16 + l15;
      af[m] = *(const short8*)&Asm[row*32 + ((lg ^ (row&3))<<3)];
    }
    #pragma unroll
    for (int q=0;q<4;++q){
      int row = wx*64 + q*16 + l15;
      bf_[q] = *(const short8*)&Bsm[row*32 + ((lg ^ (row&3))<<3)];
    }
    #pragma unroll
    for (int m=0;m<4;++m)
      #pragma unroll
      for (int q=0;q<4;++q)
        acc[m][q] = __builtin_amdgcn_mfma_f32_16x16x32_bf16(af[m], bf_[q], acc[m][q], 0,0,0);
    __syncthreads();
  }

  #pragma unroll
  for (int m=0;m<4;++m){
    const int s = tm*8 + wy*4 + m;
    #pragma unroll
    for (int q=0;q<4;++q){
      const int n = tn*128 + wx*64 + q*16 + l15;
      const float bias = bpost[n];
      f32x4 v = acc[m][q];
      #pragma unroll
      for (int r=0;r<4;++r){
        const int b = lg*4 + r;
        y[((size_t)b << 20) + ((size_t)s << 10) + n] = v[r] + bias;
      }
    }
  }
}

extern "C" void kernel_launch(void* const* d_in, const int* in_sizes, int n_in,
                              void* d_out, int out_size, void* d_ws, size_t ws_size,
                              hipStream_t stream)
{
  const float* f_in = (const float*)d_in[0];
  const float* i_in = (const float*)d_in[1];
  const float* z_in = (const float*)d_in[2];
  const float* o_in = (const float*)d_in[3];
  const float* c0   = (const float*)d_in[4];
  const float* h0   = (const float*)d_in[5];
  const float* W_Fx = (const float*)d_in[6];  const float* b_Fx = (const float*)d_in[7];
  const float* W_Ix = (const float*)d_in[8];  const float* b_Ix = (const float*)d_in[9];
  const float* W_Zx = (const float*)d_in[10]; const float* b_Zx = (const float*)d_in[11];
  const float* W_Ox = (const float*)d_in[12]; const float* b_Ox = (const float*)d_in[13];
  const float* W_Fh = (const float*)d_in[14]; const float* b_Fh = (const float*)d_in[15];
  const float* W_Ih = (const float*)d_in[16]; const float* b_Ih = (const float*)d_in[17];
  const float* W_Zh = (const float*)d_in[18]; const float* b_Zh = (const float*)d_in[19];
  const float* W_Oh = (const float*)d_in[20]; const float* b_Oh = (const float*)d_in[21];
  const float* W_post = (const float*)d_in[22]; const float* b_post = (const float*)d_in[23];

  char* ws = (char*)d_ws;
  unsigned short* xg    = (unsigned short*)(ws);
  unsigned short* hs    = (unsigned short*)(ws + XG_BYTES);
  unsigned*       flags = (unsigned*)(ws + FLAGS_OFF);
  unsigned short* wt    = (unsigned short*)(ws + WT_OFF);

  float* y  = (float*)d_out;
  float* oc = y + 16777216;   // 16*1024*1024
  float* oh = oc + 16384;

  hipMemsetAsync(flags, 0, 4096, stream);
  k_prep<<<dim3(16,16,9), 256, 0, stream>>>(W_Fx, W_Ix, W_Zx, W_Ox, W_post,
                                            W_Fh, W_Ih, W_Zh, W_Oh, wt);
  k_init<<<64, 256, 0, stream>>>(h0, hs);
  k_fill<<<8192, 256, 0, stream>>>((unsigned*)hs);
  k_xproj<<<dim3(128,8,4), 256, 0, stream>>>(f_in, i_in, z_in, o_in,
                                             b_Fx, b_Ix, b_Zx, b_Ox, wt, xg);
  k_recur<<<32, 256, 0, stream>>>(wt + (size_t)5*1024*1024,
                                  b_Fh, b_Ih, b_Zh, b_Oh,
                                  c0, xg, hs, flags, oc, oh);
  k_post<<<dim3(128,8), 256, 0, stream>>>(hs, wt, b_post, y);
}

// Round 7
// 4441.193 us; speedup vs baseline: 1.1416x; 1.1416x over previous
//
#include <hip/hip_runtime.h>
#include <stdint.h>
#include <stddef.h>

typedef __attribute__((ext_vector_type(8))) short short8;
typedef __attribute__((ext_vector_type(4))) short short4_t;
typedef __attribute__((ext_vector_type(8))) unsigned short ushort8_t;
typedef __attribute__((ext_vector_type(4))) unsigned short ushort4_t;
typedef __attribute__((ext_vector_type(4))) float f32x4;
typedef __attribute__((ext_vector_type(4))) unsigned uint4_t;

// workspace layout (bytes)
#define XG_BYTES  (134217728ull)          // xg: [1024 t][4 g][1024 n][16 b] bf16
#define HS_BYTES  (33587200ull)           // hs: [1025 t][16 b][1024 k] bf16
#define FLAGS_OFF (XG_BYTES + HS_BYTES)   // 256 flags (wg*4+wave), packed u32
#define WT_OFF    (FLAGS_OFF + 32768ull)  // Wt: [9][1024 n][1024 k] bf16

#define SENT 0x7FC07FC0u                  // bf16 NaN pair — h is finite, never equals this

__device__ __forceinline__ unsigned short f2b(float f){
  unsigned u = __builtin_bit_cast(unsigned, f);
  u += 0x7fffu + ((u >> 16) & 1u);
  return (unsigned short)(u >> 16);
}
__device__ __forceinline__ float b2f(unsigned short b){
  unsigned u = ((unsigned)b) << 16;
  return __builtin_bit_cast(float, u);
}
__device__ __forceinline__ float sigm(float x){ return 1.0f / (1.0f + __expf(-x)); }
__device__ __forceinline__ float tanh_(float x){ return 2.0f / (1.0f + __expf(-2.0f*x)) - 1.0f; }

// ---- coherence-point (MALL) primitives: sc0 sc1 = bypass L1 and L2 --------
__device__ __forceinline__ unsigned ld_u32_mall(const unsigned* p){
  unsigned v;
  asm volatile("global_load_dword %0, %1, off sc0 sc1\n\t"
               "s_waitcnt vmcnt(0)"
               : "=v"(v) : "v"(p) : "memory");
  return v;
}
__device__ __forceinline__ void ld_h8_mall(const unsigned short* p, short8* a){
  asm volatile(
    "global_load_dwordx4 %0, %8, off sc0 sc1\n\t"
    "global_load_dwordx4 %1, %8, off offset:64 sc0 sc1\n\t"
    "global_load_dwordx4 %2, %8, off offset:128 sc0 sc1\n\t"
    "global_load_dwordx4 %3, %8, off offset:192 sc0 sc1\n\t"
    "global_load_dwordx4 %4, %8, off offset:256 sc0 sc1\n\t"
    "global_load_dwordx4 %5, %8, off offset:320 sc0 sc1\n\t"
    "global_load_dwordx4 %6, %8, off offset:384 sc0 sc1\n\t"
    "global_load_dwordx4 %7, %8, off offset:448 sc0 sc1\n\t"
    "s_waitcnt vmcnt(0)"
    : "=&v"(a[0]), "=&v"(a[1]), "=&v"(a[2]), "=&v"(a[3]),
      "=&v"(a[4]), "=&v"(a[5]), "=&v"(a[6]), "=&v"(a[7])
    : "v"(p) : "memory");
}
__device__ __forceinline__ void st_u32_mall(unsigned* p, unsigned v){
  asm volatile("global_store_dword %0, %1, off sc0 sc1"
               :: "v"(p), "v"(v) : "memory");
}

// ---------------- weight transpose+convert: W[k][n] f32 -> Wt[n][k] bf16 ----
__global__ __launch_bounds__(256) void k_prep(
    const float* __restrict__ w0, const float* __restrict__ w1,
    const float* __restrict__ w2, const float* __restrict__ w3,
    const float* __restrict__ w4, const float* __restrict__ w5,
    const float* __restrict__ w6, const float* __restrict__ w7,
    const float* __restrict__ w8, unsigned short* __restrict__ wt)
{
  const int z = blockIdx.z;
  const float* W = (z==0)?w0:(z==1)?w1:(z==2)?w2:(z==3)?w3:(z==4)?w4:
                   (z==5)?w5:(z==6)?w6:(z==7)?w7:w8;
  unsigned short* out = wt + (size_t)z*1024*1024;
  __shared__ float tile[64][65];
  const int k0 = blockIdx.x*64, n0 = blockIdx.y*64;
  const int tid = threadIdx.x;
  {
    const int kk = tid >> 2, nn0 = (tid & 3) * 16;
    const float* src = W + (size_t)(k0+kk)*1024 + n0 + nn0;
    #pragma unroll
    for (int j=0;j<16;j+=4){
      f32x4 v = *(const f32x4*)(src + j);
      tile[kk][nn0+j+0]=v[0]; tile[kk][nn0+j+1]=v[1];
      tile[kk][nn0+j+2]=v[2]; tile[kk][nn0+j+3]=v[3];
    }
  }
  __syncthreads();
  {
    const int nn = tid >> 2, kk0 = (tid & 3) * 16;
    ushort8_t a, b;
    #pragma unroll
    for (int j=0;j<8;++j){ a[j]=f2b(tile[kk0+j][nn]); b[j]=f2b(tile[kk0+8+j][nn]); }
    unsigned short* dst = out + (size_t)(n0+nn)*1024 + k0 + kk0;
    *(ushort8_t*)dst = a;
    *(ushort8_t*)(dst+8) = b;
  }
}

// ---------------- h0 -> hs[0] bf16 ------------------------------------------
__global__ void k_init(const float* __restrict__ h0, unsigned short* __restrict__ hs){
  const int i = blockIdx.x*256 + threadIdx.x;
  hs[i] = f2b(h0[i]);
}

// ---------------- sentinel-fill hs[1..1024] ---------------------------------
__global__ void k_fill(unsigned* __restrict__ hsw){
  const size_t i = (size_t)blockIdx.x*256 + threadIdx.x;   // 2,097,152 threads
  uint4_t v = (uint4_t){SENT, SENT, SENT, SENT};
  *(uint4_t*)(hsw + 8192 + i*4) = v;                       // slot1 starts at word 8192
}

// ---------------- x projections: xg[t][g][n][b] = x @ Wx + bx (bf16 out) ----
__global__ __launch_bounds__(256,2) void k_xproj(
    const float* __restrict__ xF, const float* __restrict__ xI,
    const float* __restrict__ xZ, const float* __restrict__ xO,
    const float* __restrict__ bF, const float* __restrict__ bI,
    const float* __restrict__ bZ, const float* __restrict__ bO,
    const unsigned short* __restrict__ Wt,   // [4][n][k] bf16
    unsigned short* __restrict__ xg)
{
  const int g  = blockIdx.z;
  const int tm = blockIdx.x, tn = blockIdx.y;
  const float* X  = (g==0)?xF:(g==1)?xI:(g==2)?xZ:xO;
  const float* Bp = (g==0)?bF:(g==1)?bI:(g==2)?bZ:bO;
  const unsigned short* Wg = Wt + (size_t)g*1024*1024;

  __shared__ unsigned short Asm[128*32];
  __shared__ unsigned short Bsm[128*32];

  const int tid  = threadIdx.x;
  const int lane = tid & 63, wv = tid >> 6;
  const int l15  = lane & 15, lg = lane >> 4;
  const int wy   = wv >> 1,  wx = wv & 1;

  const int rr = tid >> 1, kq = tid & 1;
  const int ar = tm*128 + rr;
  const int ab = ar & 15, as_ = ar >> 4;
  const float* aptr = X + ((size_t)ab*1024 + as_)*1024 + kq*16;
  const unsigned short* bp_ = Wg + (size_t)(tn*128 + rr)*1024 + kq*16;
  const int s0 = kq*2;
  unsigned short* aw0 = &Asm[rr*32 + (((s0  ) ^ (rr&3))<<3)];
  unsigned short* aw1 = &Asm[rr*32 + (((s0+1) ^ (rr&3))<<3)];
  unsigned short* bw0 = &Bsm[rr*32 + (((s0  ) ^ (rr&3))<<3)];
  unsigned short* bw1 = &Bsm[rr*32 + (((s0+1) ^ (rr&3))<<3)];

  f32x4 acc[4][4];
  #pragma unroll
  for (int m=0;m<4;++m)
    #pragma unroll
    for (int q=0;q<4;++q) acc[m][q] = (f32x4){0.f,0.f,0.f,0.f};

  for (int k0=0; k0<1024; k0+=32){
    const float* ap = aptr + k0;
    f32x4 v0 = *(const f32x4*)(ap + 0);
    f32x4 v1 = *(const f32x4*)(ap + 4);
    f32x4 v2 = *(const f32x4*)(ap + 8);
    f32x4 v3 = *(const f32x4*)(ap + 12);
    ushort8_t pa, pb;
    #pragma unroll
    for (int j=0;j<4;++j){ pa[j]=f2b(v0[j]); pa[4+j]=f2b(v1[j]); pb[j]=f2b(v2[j]); pb[4+j]=f2b(v3[j]); }
    *(ushort8_t*)aw0 = pa;
    *(ushort8_t*)aw1 = pb;
    ushort8_t q0 = *(const ushort8_t*)(bp_ + k0);
    ushort8_t q1 = *(const ushort8_t*)(bp_ + k0 + 8);
    *(ushort8_t*)bw0 = q0;
    *(ushort8_t*)bw1 = q1;
    __syncthreads();

    short8 af[4], bf_[4];
    #pragma unroll
    for (int m=0;m<4;++m){
      int row = wy*64 + m*16 + l15;
      af[m] = *(const short8*)&Asm[row*32 + ((lg ^ (row&3))<<3)];
    }
    #pragma unroll
    for (int q=0;q<4;++q){
      int row = wx*64 + q*16 + l15;
      bf_[q] = *(const short8*)&Bsm[row*32 + ((lg ^ (row&3))<<3)];
    }
    #pragma unroll
    for (int m=0;m<4;++m)
      #pragma unroll
      for (int q=0;q<4;++q)
        acc[m][q] = __builtin_amdgcn_mfma_f32_16x16x32_bf16(af[m], bf_[q], acc[m][q], 0,0,0);
    __syncthreads();
  }

  #pragma unroll
  for (int m=0;m<4;++m){
    const int t = tm*8 + wy*4 + m;
    #pragma unroll
    for (int q=0;q<4;++q){
      const int n = tn*128 + wx*64 + q*16 + l15;
      const float bias = Bp[n];
      f32x4 v = acc[m][q];
      ushort4_t pk;
      #pragma unroll
      for (int r=0;r<4;++r) pk[r] = f2b(v[r] + bias);
      *(ushort4_t*)(xg + (size_t)((t*4+g)*1024 + n)*16 + lg*4) = pk;
    }
  }
}

// ---------------- persistent recurrence --------------------------------------
// 64 WGs; WG wg owns output cols [wg*16,+16); wave wv holds K-slice [wv*256,+256)
// in 128 weight VGPRs (R5 budget). Consumer: speculative bulk load; on sentinel,
// cheap 1-dword/lane flag poll (lane <-> producer (WG,wave) bijection), reload.
// Producer: wave wv gates ONLY component r=wv (rows lg*4+wv), stores h words +
// flag, no drain. Component-plane LDS reduce; raw lgkmcnt barrier (no VM drain).
__global__ __launch_bounds__(256,1) void k_recur(
    const unsigned short* __restrict__ WtR,   // [4][1024 n][1024 k] bf16 (Fh,Ih,Zh,Oh)
    const float* __restrict__ bfh, const float* __restrict__ bih,
    const float* __restrict__ bzh, const float* __restrict__ boh,
    const float* __restrict__ c0,
    const unsigned short* __restrict__ xg,
    unsigned short* __restrict__ hs,
    unsigned* __restrict__ flags,
    float* __restrict__ oc, float* __restrict__ oh)
{
  const int wg   = blockIdx.x;          // 0..63
  const int tid  = threadIdx.x;
  const int wv   = tid >> 6, lane = tid & 63;
  const int l15  = lane & 15, lg = lane >> 4;
  const int n    = wg*16 + l15;
  const int row  = lg*4 + wv;           // the one batch row this lane gates
  const int sh   = wv * 16;             // component-extract shift for xq words

  // register-resident recurrent weights (pre-transposed bf16, coalesced)
  short8 wf[4][8];
  #pragma unroll
  for (int g=0; g<4; ++g){
    const unsigned short* wp = WtR + (size_t)g*1048576 + (size_t)n*1024 + wv*256 + lg*8;
    #pragma unroll
    for (int c=0; c<8; ++c)
      wf[g][c] = *(const short8*)(wp + c*32);
  }

  // gating state: single (row, col) per lane
  float cst = c0[(size_t)row*1024 + n];
  float bias0 = bfh[n], bias1 = bih[n], bias2 = bzh[n], bias3 = boh[n];

  // partials as component planes: [pb][wave][gate][comp][lane]  (32 KB)
  __shared__ float part[2][4][4][4][64];

  unsigned* hsw = (unsigned*)hs;
  const unsigned* myflag = flags + wv*64 + lane;   // this wave's 64 producers

  // xq prologue (t = 0): rows lg*4..+3 for col n, per gate
  short4_t xq[4];
  #pragma unroll
  for (int g=0; g<4; ++g)
    xq[g] = *(const short4_t*)(xg + (size_t)(g*1024 + n)*16 + lg*4);

  float hv = 0.f;
  for (int t=0; t<1024; ++t){
    // 1. speculative bulk A-fragment load; cheap flag poll on sentinel
    const unsigned short* hp = hs + (size_t)t*16384 + (size_t)l15*1024 + wv*256 + lg*8;
    short8 a[8];
    ld_h8_mall(hp, a);
    {
      bool bad = false;
      #pragma unroll
      for (int c=0;c<8;++c){
        uint4_t q = __builtin_bit_cast(uint4_t, a[c]);
        bad |= (q[0]==SENT)|(q[1]==SENT)|(q[2]==SENT)|(q[3]==SENT);
      }
      if (__any(bad)){
        // flag-gated wait: 1 dword per lane per retry (64x cheaper than data)
        unsigned fv;
        do { fv = ld_u32_mall(myflag); } while (!__all((int)(fv >= (unsigned)t)));
        ld_h8_mall(hp, a);
        // paranoid backstop (flag can outrun data: no producer drain)
        for(;;){
          bad = false;
          #pragma unroll
          for (int c=0;c<8;++c){
            uint4_t q = __builtin_bit_cast(uint4_t, a[c]);
            bad |= (q[0]==SENT)|(q[1]==SENT)|(q[2]==SENT)|(q[3]==SENT);
          }
          if (!__any(bad)) break;
          __builtin_amdgcn_s_sleep(1);
          ld_h8_mall(hp, a);
        }
      }
    }

    // 2. xq(t+1) prefetch (plain cached loads; stay in flight across barrier)
    short4_t xq_n[4];
    if (t < 1023){
      const size_t tb = (size_t)(t+1)*4096;
      #pragma unroll
      for (int g=0; g<4; ++g)
        xq_n[g] = *(const short4_t*)(xg + (tb + (size_t)g*1024 + n)*16 + lg*4);
    }

    // 3. MFMA: 4 gates x 8 K-chunks
    f32x4 acc[4];
    #pragma unroll
    for (int g=0;g<4;++g) acc[g] = (f32x4){0.f,0.f,0.f,0.f};
    #pragma unroll
    for (int c=0;c<8;++c){
      acc[0] = __builtin_amdgcn_mfma_f32_16x16x32_bf16(a[c], wf[0][c], acc[0], 0,0,0);
      acc[1] = __builtin_amdgcn_mfma_f32_16x16x32_bf16(a[c], wf[1][c], acc[1], 0,0,0);
      acc[2] = __builtin_amdgcn_mfma_f32_16x16x32_bf16(a[c], wf[2][c], acc[2], 0,0,0);
      acc[3] = __builtin_amdgcn_mfma_f32_16x16x32_bf16(a[c], wf[3][c], acc[3], 0,0,0);
    }

    // 4. partial store (component planes) + raw barrier (no VMEM drain)
    const int pb = t & 1;
    #pragma unroll
    for (int g=0;g<4;++g)
      #pragma unroll
      for (int cm=0;cm<4;++cm)
        part[pb][wv][g][cm][lane] = acc[g][cm];
    asm volatile("s_waitcnt lgkmcnt(0)" ::: "memory");
    __builtin_amdgcn_s_barrier();

    // 5. reduce only component wv (this lane's batch row), conflict-free
    float rg[4];
    #pragma unroll
    for (int g=0;g<4;++g)
      rg[g] = (part[pb][0][g][wv][lane] + part[pb][1][g][wv][lane])
            + (part[pb][2][g][wv][lane] + part[pb][3][g][wv][lane]);

    // 6. gate the single (row, col)
    {
      float pf = rg[0] + b2f((unsigned short)(__builtin_bit_cast(unsigned long long, xq[0]) >> sh)) + bias0;
      float pi = rg[1] + b2f((unsigned short)(__builtin_bit_cast(unsigned long long, xq[1]) >> sh)) + bias1;
      float pz = rg[2] + b2f((unsigned short)(__builtin_bit_cast(unsigned long long, xq[2]) >> sh)) + bias2;
      float po = rg[3] + b2f((unsigned short)(__builtin_bit_cast(unsigned long long, xq[3]) >> sh)) + bias3;
      float fg = sigm(pf), ig = sigm(pi), zg = tanh_(pz), og = sigm(po);
      float cn = fg*cst + ig*zg;
      cst = cn;
      hv = og * tanh_(cn);
    }

    // 7. pack bf16 pairs across lane^1 (same row, col n^1); even lanes store
    {
      unsigned m  = (unsigned)f2b(hv);
      unsigned nb = (unsigned)__shfl_xor(m, 1);
      if ((l15 & 1) == 0){
        unsigned* pw = hsw + (size_t)(t+1)*8192 + (size_t)row*512 + (n >> 1);
        st_u32_mall(pw, m | (nb << 16));
      }
      if (lane == 0)
        st_u32_mall(flags + wg*4 + wv, (unsigned)(t+1));
    }

    // 8. rotate xq pipeline
    #pragma unroll
    for (int g=0; g<4; ++g) xq[g] = xq_n[g];
  }

  // final state: each lane owns one (row, col)
  oc[(size_t)row*1024 + n] = cst;
  oh[(size_t)row*1024 + n] = hv;
}

// ---------------- post projection: y[b][s][n] = hs[1..] @ Wpost + bpost -----
__global__ __launch_bounds__(256,2) void k_post(
    const unsigned short* __restrict__ hs,
    const unsigned short* __restrict__ Wt,   // post slice at +4M
    const float* __restrict__ bpost,
    float* __restrict__ y)
{
  const int tm = blockIdx.x, tn = blockIdx.y;
  __shared__ unsigned short Asm[128*32];
  __shared__ unsigned short Bsm[128*32];

  const int tid  = threadIdx.x;
  const int lane = tid & 63, wv = tid >> 6;
  const int l15  = lane & 15, lg = lane >> 4;
  const int wy   = wv >> 1,  wx = wv & 1;

  const int rr = tid >> 1, kq = tid & 1;
  const unsigned short* aptr = hs + 16384 + (size_t)(tm*128 + rr)*1024 + kq*16;
  const unsigned short* bp_  = Wt + (size_t)4*1024*1024 + (size_t)(tn*128 + rr)*1024 + kq*16;
  const int s0 = kq*2;
  unsigned short* aw0 = &Asm[rr*32 + (((s0  ) ^ (rr&3))<<3)];
  unsigned short* aw1 = &Asm[rr*32 + (((s0+1) ^ (rr&3))<<3)];
  unsigned short* bw0 = &Bsm[rr*32 + (((s0  ) ^ (rr&3))<<3)];
  unsigned short* bw1 = &Bsm[rr*32 + (((s0+1) ^ (rr&3))<<3)];

  f32x4 acc[4][4];
  #pragma unroll
  for (int m=0;m<4;++m)
    #pragma unroll
    for (int q=0;q<4;++q) acc[m][q] = (f32x4){0.f,0.f,0.f,0.f};

  for (int k0=0; k0<1024; k0+=32){
    ushort8_t a0 = *(const ushort8_t*)(aptr + k0);
    ushort8_t a1 = *(const ushort8_t*)(aptr + k0 + 8);
    *(ushort8_t*)aw0 = a0;
    *(ushort8_t*)aw1 = a1;
    ushort8_t q0 = *(const ushort8_t*)(bp_ + k0);
    ushort8_t q1 = *(const ushort8_t*)(bp_ + k0 + 8);
    *(ushort8_t*)bw0 = q0;
    *(ushort8_t*)bw1 = q1;
    __syncthreads();

    short8 af[4], bf_[4];
    #pragma unroll
    for (int m=0;m<4;++m){
      int row = wy*64 + m*16 + l15;
      af[m] = *(const short8*)&Asm[row*32 + ((lg ^ (row&3))<<3)];
    }
    #pragma unroll
    for (int q=0;q<4;++q){
      int row = wx*64 + q*16 + l15;
      bf_[q] = *(const short8*)&Bsm[row*32 + ((lg ^ (row&3))<<3)];
    }
    #pragma unroll
    for (int m=0;m<4;++m)
      #pragma unroll
      for (int q=0;q<4;++q)
        acc[m][q] = __builtin_amdgcn_mfma_f32_16x16x32_bf16(af[m], bf_[q], acc[m][q], 0,0,0);
    __syncthreads();
  }

  #pragma unroll
  for (int m=0;m<4;++m){
    const int s = tm*8 + wy*4 + m;
    #pragma unroll
    for (int q=0;q<4;++q){
      const int n = tn*128 + wx*64 + q*16 + l15;
      const float bias = bpost[n];
      f32x4 v = acc[m][q];
      #pragma unroll
      for (int r=0;r<4;++r){
        const int b = lg*4 + r;
        y[((size_t)b << 20) + ((size_t)s << 10) + n] = v[r] + bias;
      }
    }
  }
}

extern "C" void kernel_launch(void* const* d_in, const int* in_sizes, int n_in,
                              void* d_out, int out_size, void* d_ws, size_t ws_size,
                              hipStream_t stream)
{
  const float* f_in = (const float*)d_in[0];
  const float* i_in = (const float*)d_in[1];
  const float* z_in = (const float*)d_in[2];
  const float* o_in = (const float*)d_in[3];
  const float* c0   = (const float*)d_in[4];
  const float* h0   = (const float*)d_in[5];
  const float* W_Fx = (const float*)d_in[6];  const float* b_Fx = (const float*)d_in[7];
  const float* W_Ix = (const float*)d_in[8];  const float* b_Ix = (const float*)d_in[9];
  const float* W_Zx = (const float*)d_in[10]; const float* b_Zx = (const float*)d_in[11];
  const float* W_Ox = (const float*)d_in[12]; const float* b_Ox = (const float*)d_in[13];
  const float* W_Fh = (const float*)d_in[14]; const float* b_Fh = (const float*)d_in[15];
  const float* W_Ih = (const float*)d_in[16]; const float* b_Ih = (const float*)d_in[17];
  const float* W_Zh = (const float*)d_in[18]; const float* b_Zh = (const float*)d_in[19];
  const float* W_Oh = (const float*)d_in[20]; const float* b_Oh = (const float*)d_in[21];
  const float* W_post = (const float*)d_in[22]; const float* b_post = (const float*)d_in[23];

  char* ws = (char*)d_ws;
  unsigned short* xg    = (unsigned short*)(ws);
  unsigned short* hs    = (unsigned short*)(ws + XG_BYTES);
  unsigned*       flags = (unsigned*)(ws + FLAGS_OFF);
  unsigned short* wt    = (unsigned short*)(ws + WT_OFF);

  float* y  = (float*)d_out;
  float* oc = y + 16777216;   // 16*1024*1024
  float* oh = oc + 16384;

  hipMemsetAsync(flags, 0, 4096, stream);
  k_prep<<<dim3(16,16,9), 256, 0, stream>>>(W_Fx, W_Ix, W_Zx, W_Ox, W_post,
                                            W_Fh, W_Ih, W_Zh, W_Oh, wt);
  k_init<<<64, 256, 0, stream>>>(h0, hs);
  k_fill<<<8192, 256, 0, stream>>>((unsigned*)hs);
  k_xproj<<<dim3(128,8,4), 256, 0, stream>>>(f_in, i_in, z_in, o_in,
                                             b_Fx, b_Ix, b_Zx, b_Ox, wt, xg);
  k_recur<<<64, 256, 0, stream>>>(wt + (size_t)5*1024*1024,
                                  b_Fh, b_Ih, b_Zh, b_Oh,
                                  c0, xg, hs, flags, oc, oh);
  k_post<<<dim3(128,8), 256, 0, stream>>>(hs, wt, b_post, y);
}